// Round 1
// baseline (265.144 us; speedup 1.0000x reference)
//
#include <hip/hip_runtime.h>

// DepConv3D, fused single-pass version.
//   diff = depth[nbr]-depth[center]; kd=0 iff diff==-1, kd=1 iff diff==0, else 0.
// Block = 256 px of one image row. Stage 3x258 halo tile (bf16 pixel-major
// features + int depth) in LDS once, then 9-tap MFMA loop reads LDS only:
// every tap address is one base VGPR + compile-time immediate offset.
// MFMA 16x16x32_bf16 conventions (validated by the previous passing kernels):
//   A: m=lane&15 (oc), kk=(lane>>4)*8+j ; B: n=lane&15 (pixel), kk same
//   D: col=lane&15 (pixel), row=(lane>>4)*4+r (oc)

#define IC 16
#define OC 32
#define Hh 512
#define Ww 512
#define HW (Hh * Ww)

typedef __attribute__((ext_vector_type(8))) short short8;
typedef __attribute__((ext_vector_type(4))) float float4v;
typedef __attribute__((ext_vector_type(2))) unsigned int uint2v;

__device__ __forceinline__ unsigned short f2bf(float x) {
    unsigned u = __float_as_uint(x);
    unsigned r = u + 0x7FFFu + ((u >> 16) & 1u);   // RNE
    return (unsigned short)(r >> 16);
}

// ---- prepass: fp32 weights (32,16,3,3,3) -> bf16 A-fragments ----
__global__ void prep_weights(const float* __restrict__ wgt,
                             unsigned short* __restrict__ wsA) {
    int e = blockIdx.x * 256 + threadIdx.x;
    if (e >= 9 * 2 * 64 * 8) return;
    int j    = e & 7;
    int lane = (e >> 3) & 63;
    int mt   = (e >> 9) & 1;
    int c    = e >> 10;
    int oc = mt * 16 + (lane & 15);
    int kk = ((lane >> 4) << 3) + j;
    wsA[e] = f2bf(wgt[oc * 432 + (kk >> 1) * 27 + (kk & 1) * 9 + c]);
}

// ---- fused main kernel: LDS halo tile, no intermediate global buffer ----
__global__ __launch_bounds__(256) void depconv_fused(
    const float* __restrict__ feat,           // (4,16,512,512) fp32
    const int*   __restrict__ depth,          // (4,512,512)
    const unsigned short* __restrict__ wsA,
    float*       __restrict__ out)            // (4,32,512,512)
{
    __shared__ unsigned short ftile[3][258][IC];   // 24,768 B, bf16 pixel-major
    __shared__ int            dtile[3][258];       //  3,096 B

    const int tid  = threadIdx.x;
    const int lane = tid & 63;
    const int wv   = tid >> 6;
    const int g    = lane >> 4;   // ic-group: ics 4g..4g+3
    const int n    = lane & 15;

    // XCD-aware swizzle: 4096 blocks, 8 XCDs, 4096%8==0 -> bijective chunks.
    const int bid = blockIdx.x;
    const int wg  = (bid & 7) * (4096 / 8) + (bid >> 3);

    const int P0     = wg * 256;
    const int b      = P0 >> 18;
    const int hw0    = P0 & (HW - 1);
    const int h      = hw0 >> 9;
    const int wstart = hw0 & (Ww - 1);      // 0 or 256

    const int y0 = (h == 0) ? 0 : h - 1;
    const int y2 = (h == Hh - 1) ? Hh - 1 : h + 1;
    const int yrs[3] = {y0, h, y2};

    // ---- stage halo tile: xl in [0,258) maps to global x = wstart-1+xl,
    //      clamped (clamped values are never consumed: boundary mask = 0) ----
    {
        const int x  = wstart - 1 + tid;
        const int xc = x < 0 ? 0 : (x > Ww - 1 ? Ww - 1 : x);
        const int xt = wstart - 1 + 256 + tid;           // tail xl = 256,257
        const int xct = xt > Ww - 1 ? Ww - 1 : xt;
#pragma unroll
        for (int r = 0; r < 3; ++r) {
            const float* fpl = feat + (size_t)b * IC * HW + (size_t)yrs[r] * Ww;
            const int*   dpl = depth + (b << 18) + yrs[r] * Ww;
            dtile[r][tid] = dpl[xc];
            if (tid < 2) dtile[r][256 + tid] = dpl[xct];
#pragma unroll
            for (int icp = 0; icp < 8; ++icp) {
                float a = fpl[(size_t)(2 * icp) * HW + xc];
                float c = fpl[(size_t)(2 * icp + 1) * HW + xc];
                *(unsigned*)&ftile[r][tid][2 * icp] =
                    (unsigned)f2bf(a) | ((unsigned)f2bf(c) << 16);
                if (tid < 2) {
                    float at = fpl[(size_t)(2 * icp) * HW + xct];
                    float ct = fpl[(size_t)(2 * icp + 1) * HW + xct];
                    *(unsigned*)&ftile[r][256 + tid][2 * icp] =
                        (unsigned)f2bf(at) | ((unsigned)f2bf(ct) << 16);
                }
            }
        }
    }

    // A-fragments (overlaps with staging loads; no LDS dependency)
    short8 afrag[9][2];
    {
        const short8* ap = (const short8*)wsA;
#pragma unroll
        for (int c = 0; c < 9; ++c) {
            afrag[c][0] = ap[(c * 2 + 0) * 64 + lane];
            afrag[c][1] = ap[(c * 2 + 1) * 64 + lane];
        }
    }
    __syncthreads();

    for (int it = 0; it < 4; ++it) {
        const int xb = wv * 64 + it * 16 + n;     // local pixel idx [0,256)
        const int w  = wstart + xb;               // global column
        const int dc = dtile[1][xb + 1];

        float4v acc0 = {0.f, 0.f, 0.f, 0.f};
        float4v acc1 = {0.f, 0.f, 0.f, 0.f};

#pragma unroll
        for (int t = 0; t < 9; ++t) {
            const int kh = t / 3, kw = t % 3;
            unsigned mm;
            if (t == 4) {
                mm = 0xffff0000u;   // center: diff==0 always, kd=1 slice
            } else {
                const bool inb = !((kh == 0 && h == 0) || (kh == 2 && h == Hh - 1) ||
                                   (kw == 0 && w == 0) || (kw == 2 && w == Ww - 1));
                const int diff = dtile[kh][xb + kw] - dc;
                mm = (diff == 0) ? 0xffff0000u : ((diff == -1) ? 0x0000ffffu : 0u);
                if (!inb) mm = 0u;
            }
            // 4 ics of this lane's neighbor pixel: one 8 B LDS read,
            // address = single base VGPR + immediate (kh,kw folded).
            const uint2v pr = *(const uint2v*)(&ftile[kh][xb + kw][g << 2]);
            union { short8 s; unsigned u[4]; } bf;
            bf.u[0] = __builtin_amdgcn_perm(0u, pr.x, 0x01000100u) & mm;  // ic 4g+0
            bf.u[1] = __builtin_amdgcn_perm(0u, pr.x, 0x03020302u) & mm;  // ic 4g+1
            bf.u[2] = __builtin_amdgcn_perm(0u, pr.y, 0x01000100u) & mm;  // ic 4g+2
            bf.u[3] = __builtin_amdgcn_perm(0u, pr.y, 0x03020302u) & mm;  // ic 4g+3

            acc0 = __builtin_amdgcn_mfma_f32_16x16x32_bf16(afrag[t][0], bf.s, acc0, 0, 0, 0);
            acc1 = __builtin_amdgcn_mfma_f32_16x16x32_bf16(afrag[t][1], bf.s, acc1, 0, 0, 0);
        }

        const int rbase = g * 4;
        float* op = out + ((size_t)(b * OC) << 18) + h * Ww + w;
#pragma unroll
        for (int r = 0; r < 4; ++r) {
            op[(size_t)(rbase + r) * HW]      = acc0[r];
            op[(size_t)(16 + rbase + r) * HW] = acc1[r];
        }
    }
}

extern "C" void kernel_launch(void* const* d_in, const int* in_sizes, int n_in,
                              void* d_out, int out_size, void* d_ws, size_t ws_size,
                              hipStream_t stream) {
    const float* feat  = (const float*)d_in[0];
    const int*   depth = (const int*)d_in[1];
    const float* wgt   = (const float*)d_in[2];
    float* out = (float*)d_out;

    unsigned short* wsA = (unsigned short*)d_ws;     // 18,432 B only

    prep_weights<<<36, 256, 0, stream>>>(wgt, wsA);
    depconv_fused<<<4096, 256, 0, stream>>>(feat, depth, wsA, out);
}